// Round 1
// baseline (683.723 us; speedup 1.0000x reference)
//
#include <hip/hip_runtime.h>
#include <hip/hip_bf16.h>

#define BATCH   2
#define SEQ     512
#define DMODEL  1024
#define DSTATE  64
#define HEADDIM 64
#define DCONV   4
#define VNUM    3
#define HORIZON 20
#define DINNER  2048
#define NHEADS  32
#define CONVDIM 2176   // DINNER + 2*DSTATE
#define DINPROJ 4256   // 2*DINNER + 2*DSTATE + NHEADS
#define BS      (BATCH*SEQ)   // 1024
#define RMS_EPS 1e-5f

// ---------------------------------------------------------------------------
// Tiled NT GEMM (fp32): C[M,N] = A[M,K] * B[N,K]^T, A/B row-major, K-major.
// 64x64 block tile, 256 threads, 4x4 per thread, K-tile 16.
// M % 64 == 0 and K % 16 == 0 assumed; N guarded (N % 4 == 0 assumed).
// ---------------------------------------------------------------------------
template<int M, int N, int K>
__global__ __launch_bounds__(256) void gemm_nt(const float* __restrict__ A,
                                               const float* __restrict__ B,
                                               float* __restrict__ C) {
    __shared__ float As[16][64];
    __shared__ float Bs[16][64];
    const int tid  = threadIdx.x;
    const int row0 = blockIdx.y * 64;
    const int col0 = blockIdx.x * 64;
    const int tm = tid >> 4;       // 0..15
    const int tn = tid & 15;       // 0..15

    const int lrow = tid >> 2;        // 0..63
    const int lk   = (tid & 3) * 4;   // 0,4,8,12

    const float* Aptr = A + (size_t)(row0 + lrow) * K + lk;
    const float* Bptr = B + (size_t)(col0 + lrow) * K + lk;
    const bool bvalid = (col0 + lrow) < N;

    float acc[4][4];
#pragma unroll
    for (int i = 0; i < 4; ++i)
#pragma unroll
        for (int j = 0; j < 4; ++j) acc[i][j] = 0.f;

    for (int k0 = 0; k0 < K; k0 += 16) {
        float4 av = *(const float4*)(Aptr + k0);
        float4 bv = bvalid ? *(const float4*)(Bptr + k0)
                           : make_float4(0.f, 0.f, 0.f, 0.f);
        __syncthreads();   // previous iteration's reads complete
        As[lk + 0][lrow] = av.x; As[lk + 1][lrow] = av.y;
        As[lk + 2][lrow] = av.z; As[lk + 3][lrow] = av.w;
        Bs[lk + 0][lrow] = bv.x; Bs[lk + 1][lrow] = bv.y;
        Bs[lk + 2][lrow] = bv.z; Bs[lk + 3][lrow] = bv.w;
        __syncthreads();
#pragma unroll
        for (int k = 0; k < 16; ++k) {
            float4 a4 = *(const float4*)&As[k][tm * 4];
            float4 b4 = *(const float4*)&Bs[k][tn * 4];
            float a[4] = {a4.x, a4.y, a4.z, a4.w};
            float b[4] = {b4.x, b4.y, b4.z, b4.w};
#pragma unroll
            for (int i = 0; i < 4; ++i)
#pragma unroll
                for (int j = 0; j < 4; ++j) acc[i][j] += a[i] * b[j];
        }
    }

    if (col0 + tn * 4 < N) {
#pragma unroll
        for (int i = 0; i < 4; ++i) {
            const int r = row0 + tm * 4 + i;
            float4 v = make_float4(acc[i][0], acc[i][1], acc[i][2], acc[i][3]);
            *(float4*)&C[(size_t)r * N + col0 + tn * 4] = v;
        }
    }
}

// ---------------------------------------------------------------------------
// Causal conv1d (width 4) + bias + SiLU over the xBC slice of zxbcdt.
// ---------------------------------------------------------------------------
__global__ __launch_bounds__(256) void conv_silu_kernel(
        const float* __restrict__ zxbcdt, const float* __restrict__ cw,
        const float* __restrict__ cb, float* __restrict__ xbc) {
    const int idx = blockIdx.x * 256 + threadIdx.x;
    if (idx >= BS * CONVDIM) return;
    const int c  = idx % CONVDIM;
    const int rs = idx / CONVDIM;
    const int s  = rs % SEQ;
    const float* src = zxbcdt + (size_t)rs * DINPROJ + DINNER + c;
    float acc = cb[c];
    const float w0 = cw[c * 4 + 0], w1 = cw[c * 4 + 1];
    const float w2 = cw[c * 4 + 2], w3 = cw[c * 4 + 3];
    if (s >= 3) acc += w0 * src[-3 * DINPROJ];
    if (s >= 2) acc += w1 * src[-2 * DINPROJ];
    if (s >= 1) acc += w2 * src[-1 * DINPROJ];
    acc += w3 * src[0];
    acc = acc / (1.f + expf(-acc));   // SiLU
    xbc[(size_t)rs * CONVDIM + c] = acc;
}

// ---------------------------------------------------------------------------
// dt = softplus(dt_raw + dt_bias)
// ---------------------------------------------------------------------------
__global__ __launch_bounds__(256) void dt_softplus_kernel(
        const float* __restrict__ zxbcdt, const float* __restrict__ dt_bias,
        float* __restrict__ dts) {
    const int idx = blockIdx.x * 256 + threadIdx.x;
    if (idx >= BS * NHEADS) return;
    const int h  = idx % NHEADS;
    const int rs = idx / NHEADS;
    const float v = zxbcdt[(size_t)rs * DINPROJ + DINNER + CONVDIM + h] + dt_bias[h];
    // numerically-stable softplus
    const float sp = fmaxf(v, 0.f) + log1pf(expf(-fabsf(v)));
    dts[idx] = sp;
}

// ---------------------------------------------------------------------------
// Selective-state scan. One block per (b,h). 256 threads = 64 p-lanes x 4
// state groups of 16 n each. State lives in registers (16 f32 per thread).
// ---------------------------------------------------------------------------
__global__ __launch_bounds__(256) void scan_kernel(
        const float* __restrict__ xbc, const float* __restrict__ dts,
        const float* __restrict__ A_log, const float* __restrict__ Dv,
        float* __restrict__ yraw) {
    const int bh = blockIdx.x;      // 0..63
    const int b  = bh >> 5;
    const int h  = bh & 31;
    const int t  = threadIdx.x;
    const int p  = t & 63;          // headdim lane
    const int ng = t >> 6;          // state group 0..3

    __shared__ float sB[64], sC[64];
    __shared__ float part[4][64];

    const float A  = -expf(A_log[h]);
    const float Dh = Dv[h];

    float hs[16];
#pragma unroll
    for (int n = 0; n < 16; ++n) hs[n] = 0.f;

    const float* base = xbc + (size_t)b * SEQ * CONVDIM;
    const float* dtb  = dts + (size_t)b * SEQ * NHEADS + h;
    float* yout = yraw + (size_t)b * SEQ * DINNER + h * HEADDIM + p;

    for (int s = 0; s < SEQ; ++s) {
        const float* rowp = base + (size_t)s * CONVDIM;
        const float dt = dtb[s * NHEADS];
        const float xp = rowp[h * HEADDIM + p];
        if (ng == 0) {
            sB[p] = rowp[DINNER + p];
            sC[p] = rowp[DINNER + DSTATE + p];
        }
        __syncthreads();   // sB/sC ready
        const float dA   = expf(dt * A);
        const float coef = dt * xp;
        float y = 0.f;
#pragma unroll
        for (int q = 0; q < 4; ++q) {
            float4 bq = *(const float4*)&sB[ng * 16 + q * 4];
            float4 cq = *(const float4*)&sC[ng * 16 + q * 4];
            hs[q*4+0] = hs[q*4+0] * dA + coef * bq.x;  y += hs[q*4+0] * cq.x;
            hs[q*4+1] = hs[q*4+1] * dA + coef * bq.y;  y += hs[q*4+1] * cq.y;
            hs[q*4+2] = hs[q*4+2] * dA + coef * bq.z;  y += hs[q*4+2] * cq.z;
            hs[q*4+3] = hs[q*4+3] * dA + coef * bq.w;  y += hs[q*4+3] * cq.w;
        }
        part[ng][p] = y;
        __syncthreads();   // partials ready; sB/sC reads complete
        if (ng == 0) {
            const float yt = part[0][p] + part[1][p] + part[2][p] + part[3][p];
            yout[(size_t)s * DINNER] = yt + Dh * xp;
        }
    }
}

// ---------------------------------------------------------------------------
// y = y * silu(z); y = y * rsqrt(mean(y^2) + eps) * norm_w.  In-place on yraw.
// One block per (b,s) row; 256 threads x 8 elements.
// ---------------------------------------------------------------------------
__global__ __launch_bounds__(256) void gate_norm_kernel(
        const float* __restrict__ zxbcdt, float* __restrict__ y,
        const float* __restrict__ nw) {
    const int rs = blockIdx.x;
    const int t  = threadIdx.x;
    const float* z = zxbcdt + (size_t)rs * DINPROJ;
    float* yr = y + (size_t)rs * DINNER;

    float vals[8];
    float ss = 0.f;
#pragma unroll
    for (int i = 0; i < 8; ++i) {
        const int c = t + i * 256;
        const float zv = z[c];
        const float v  = yr[c] * (zv / (1.f + expf(-zv)));
        vals[i] = v;
        ss += v * v;
    }
#pragma unroll
    for (int off = 32; off > 0; off >>= 1) ss += __shfl_down(ss, off, 64);
    __shared__ float red[4];
    if ((t & 63) == 0) red[t >> 6] = ss;
    __syncthreads();
    const float tot   = red[0] + red[1] + red[2] + red[3];
    const float scale = rsqrtf(tot / (float)DINNER + RMS_EPS);
#pragma unroll
    for (int i = 0; i < 8; ++i) {
        const int c = t + i * 256;
        yr[c] = vals[i] * scale * nw[c];
    }
}

// ---------------------------------------------------------------------------
// pred_current: out[rs,v] = dot(hout[rs,:], dec_cur_w[v,:]) + b[v], v<3
// ---------------------------------------------------------------------------
__global__ __launch_bounds__(256) void pred_cur_kernel(
        const float* __restrict__ hout, const float* __restrict__ w,
        const float* __restrict__ bvec, float* __restrict__ out) {
    const int rs = blockIdx.x;
    const int t  = threadIdx.x;
    const float* hr = hout + (size_t)rs * DMODEL;
    float p0 = 0.f, p1 = 0.f, p2 = 0.f;
    for (int i = t; i < DMODEL; i += 256) {
        const float hv = hr[i];
        p0 += hv * w[i];
        p1 += hv * w[DMODEL + i];
        p2 += hv * w[2 * DMODEL + i];
    }
#pragma unroll
    for (int off = 32; off > 0; off >>= 1) {
        p0 += __shfl_down(p0, off, 64);
        p1 += __shfl_down(p1, off, 64);
        p2 += __shfl_down(p2, off, 64);
    }
    __shared__ float red[4][3];
    if ((t & 63) == 0) {
        red[t >> 6][0] = p0; red[t >> 6][1] = p1; red[t >> 6][2] = p2;
    }
    __syncthreads();
    if (t < 3) {
        const float s = red[0][t] + red[1][t] + red[2][t] + red[3][t];
        out[(size_t)rs * VNUM + t] = s + bvec[t];
    }
}

// ---------------------------------------------------------------------------
// pred_future: one block per (b, j) ; j < HORIZON*VNUM = 60
// ---------------------------------------------------------------------------
__global__ __launch_bounds__(256) void pred_fut_kernel(
        const float* __restrict__ hout, const float* __restrict__ w,
        const float* __restrict__ bvec, float* __restrict__ out) {
    const int blk = blockIdx.x;           // b*60 + j
    const int b = blk / (HORIZON * VNUM);
    const int j = blk % (HORIZON * VNUM);
    const float* hr = hout + ((size_t)b * SEQ + (SEQ - 1)) * DMODEL;
    const float* wr = w + (size_t)j * DMODEL;
    float pv = 0.f;
    for (int i = threadIdx.x; i < DMODEL; i += 256) pv += hr[i] * wr[i];
#pragma unroll
    for (int off = 32; off > 0; off >>= 1) pv += __shfl_down(pv, off, 64);
    __shared__ float red[4];
    if ((threadIdx.x & 63) == 0) red[threadIdx.x >> 6] = pv;
    __syncthreads();
    if (threadIdx.x == 0)
        out[b * (HORIZON * VNUM) + j] = red[0] + red[1] + red[2] + red[3] + bvec[j];
}

// ---------------------------------------------------------------------------
extern "C" void kernel_launch(void* const* d_in, const int* in_sizes, int n_in,
                              void* d_out, int out_size, void* d_ws, size_t ws_size,
                              hipStream_t stream) {
    const float* embed      = (const float*)d_in[0];
    const float* in_proj_w  = (const float*)d_in[1];
    const float* conv_w     = (const float*)d_in[2];
    const float* conv_b     = (const float*)d_in[3];
    const float* dt_bias    = (const float*)d_in[4];
    const float* A_log      = (const float*)d_in[5];
    const float* Dv         = (const float*)d_in[6];
    const float* norm_w     = (const float*)d_in[7];
    const float* out_proj_w = (const float*)d_in[8];
    const float* dec_cur_w  = (const float*)d_in[9];
    const float* dec_cur_b  = (const float*)d_in[10];
    const float* dec_fut_w  = (const float*)d_in[11];
    const float* dec_fut_b  = (const float*)d_in[12];

    float* ws     = (float*)d_ws;
    float* zxbcdt = ws;                                  // BS*DINPROJ
    float* xbc    = zxbcdt + (size_t)BS * DINPROJ;       // BS*CONVDIM
    float* dts    = xbc    + (size_t)BS * CONVDIM;       // BS*NHEADS
    float* yraw   = dts    + (size_t)BS * NHEADS;        // BS*DINNER (norm in-place)
    float* hout   = yraw   + (size_t)BS * DINNER;        // BS*DMODEL

    float* out = (float*)d_out;

    // 1. in-projection GEMM: (1024 x 1024) * (4256 x 1024)^T
    gemm_nt<BS, DINPROJ, DMODEL>
        <<<dim3((DINPROJ + 63) / 64, BS / 64), 256, 0, stream>>>(embed, in_proj_w, zxbcdt);

    // 2. causal conv + SiLU ; softplus(dt)
    conv_silu_kernel<<<(BS * CONVDIM + 255) / 256, 256, 0, stream>>>(zxbcdt, conv_w, conv_b, xbc);
    dt_softplus_kernel<<<(BS * NHEADS + 255) / 256, 256, 0, stream>>>(zxbcdt, dt_bias, dts);

    // 3. selective scan
    scan_kernel<<<BATCH * NHEADS, 256, 0, stream>>>(xbc, dts, A_log, Dv, yraw);

    // 4. gate + RMSNorm (in place)
    gate_norm_kernel<<<BS, 256, 0, stream>>>(zxbcdt, yraw, norm_w);

    // 5. out-projection GEMM: (1024 x 2048) * (1024 x 2048)^T
    gemm_nt<BS, DMODEL, DINNER>
        <<<dim3(DMODEL / 64, BS / 64), 256, 0, stream>>>(yraw, out_proj_w, hout);

    // 6. decoders
    pred_cur_kernel<<<BS, 256, 0, stream>>>(hout, dec_cur_w, dec_cur_b, out);
    pred_fut_kernel<<<BATCH * HORIZON * VNUM, 256, 0, stream>>>(hout, dec_fut_w, dec_fut_b,
                                                                out + BS * VNUM);
}

// Round 2
// 402.655 us; speedup vs baseline: 1.6980x; 1.6980x over previous
//
#include <hip/hip_runtime.h>
#include <hip/hip_bf16.h>

#define BATCH   2
#define SEQ     512
#define DMODEL  1024
#define DSTATE  64
#define HEADDIM 64
#define DCONV   4
#define VNUM    3
#define HORIZON 20
#define DINNER  2048
#define NHEADS  32
#define CONVDIM 2176   // DINNER + 2*DSTATE
#define DINPROJ 4256   // 2*DINNER + 2*DSTATE + NHEADS
#define BS      (BATCH*SEQ)   // 1024
#define RMS_EPS 1e-5f
#define CHUNK   64
#define NCHUNK  (SEQ/CHUNK)   // 8

// ---------------------------------------------------------------------------
// Tiled NT GEMM (fp32): C[M,N] = A[M,K] * B[N,K]^T, A/B row-major, K-major.
// ---------------------------------------------------------------------------
template<int M, int N, int K>
__global__ __launch_bounds__(256) void gemm_nt(const float* __restrict__ A,
                                               const float* __restrict__ B,
                                               float* __restrict__ C) {
    __shared__ float As[16][64];
    __shared__ float Bs[16][64];
    const int tid  = threadIdx.x;
    const int row0 = blockIdx.y * 64;
    const int col0 = blockIdx.x * 64;
    const int tm = tid >> 4;
    const int tn = tid & 15;

    const int lrow = tid >> 2;
    const int lk   = (tid & 3) * 4;

    const float* Aptr = A + (size_t)(row0 + lrow) * K + lk;
    const float* Bptr = B + (size_t)(col0 + lrow) * K + lk;
    const bool bvalid = (col0 + lrow) < N;

    float acc[4][4];
#pragma unroll
    for (int i = 0; i < 4; ++i)
#pragma unroll
        for (int j = 0; j < 4; ++j) acc[i][j] = 0.f;

    for (int k0 = 0; k0 < K; k0 += 16) {
        float4 av = *(const float4*)(Aptr + k0);
        float4 bv = bvalid ? *(const float4*)(Bptr + k0)
                           : make_float4(0.f, 0.f, 0.f, 0.f);
        __syncthreads();
        As[lk + 0][lrow] = av.x; As[lk + 1][lrow] = av.y;
        As[lk + 2][lrow] = av.z; As[lk + 3][lrow] = av.w;
        Bs[lk + 0][lrow] = bv.x; Bs[lk + 1][lrow] = bv.y;
        Bs[lk + 2][lrow] = bv.z; Bs[lk + 3][lrow] = bv.w;
        __syncthreads();
#pragma unroll
        for (int k = 0; k < 16; ++k) {
            float4 a4 = *(const float4*)&As[k][tm * 4];
            float4 b4 = *(const float4*)&Bs[k][tn * 4];
            float a[4] = {a4.x, a4.y, a4.z, a4.w};
            float b[4] = {b4.x, b4.y, b4.z, b4.w};
#pragma unroll
            for (int i = 0; i < 4; ++i)
#pragma unroll
                for (int j = 0; j < 4; ++j) acc[i][j] += a[i] * b[j];
        }
    }

    if (col0 + tn * 4 < N) {
#pragma unroll
        for (int i = 0; i < 4; ++i) {
            const int r = row0 + tm * 4 + i;
            float4 v = make_float4(acc[i][0], acc[i][1], acc[i][2], acc[i][3]);
            *(float4*)&C[(size_t)r * N + col0 + tn * 4] = v;
        }
    }
}

// ---------------------------------------------------------------------------
// Causal conv1d (width 4) + bias + SiLU over the xBC slice of zxbcdt.
// ---------------------------------------------------------------------------
__global__ __launch_bounds__(256) void conv_silu_kernel(
        const float* __restrict__ zxbcdt, const float* __restrict__ cw,
        const float* __restrict__ cb, float* __restrict__ xbc) {
    const int idx = blockIdx.x * 256 + threadIdx.x;
    if (idx >= BS * CONVDIM) return;
    const int c  = idx % CONVDIM;
    const int rs = idx / CONVDIM;
    const int s  = rs % SEQ;
    const float* src = zxbcdt + (size_t)rs * DINPROJ + DINNER + c;
    float acc = cb[c];
    const float w0 = cw[c * 4 + 0], w1 = cw[c * 4 + 1];
    const float w2 = cw[c * 4 + 2], w3 = cw[c * 4 + 3];
    if (s >= 3) acc += w0 * src[-3 * DINPROJ];
    if (s >= 2) acc += w1 * src[-2 * DINPROJ];
    if (s >= 1) acc += w2 * src[-1 * DINPROJ];
    acc += w3 * src[0];
    acc = acc / (1.f + expf(-acc));   // SiLU
    xbc[(size_t)rs * CONVDIM + c] = acc;
}

// ---------------------------------------------------------------------------
// dt = softplus(dt_raw + dt_bias)
// ---------------------------------------------------------------------------
__global__ __launch_bounds__(256) void dt_softplus_kernel(
        const float* __restrict__ zxbcdt, const float* __restrict__ dt_bias,
        float* __restrict__ dts) {
    const int idx = blockIdx.x * 256 + threadIdx.x;
    if (idx >= BS * NHEADS) return;
    const int h  = idx % NHEADS;
    const int rs = idx / NHEADS;
    const float v = zxbcdt[(size_t)rs * DINPROJ + DINNER + CONVDIM + h] + dt_bias[h];
    const float sp = fmaxf(v, 0.f) + log1pf(expf(-fabsf(v)));
    dts[idx] = sp;
}

// ---------------------------------------------------------------------------
// Chunked SSD scan, pass A: per (b,h,chunk) block compute
//   l_t  = cumsum(dt*A) within chunk (inclusive)
//   M^T[s][t] = 1[s<=t] * exp(l_t-l_s) * (C_t . B_s)
//   Y_intra[t][p] = sum_s M[t][s] * U[s][p]  (+ D*x)   -> yraw
//   Sc[p][n] = sum_s exp(l_end-l_s) * U[s][p] * B_s[n] -> ws
//   dexp[t] = exp(l_t)                                 -> ws
// LDS: transposed [n][.] layouts (stride 68) so inner loops are float4
// broadcasts / <=2-way bank aliases.
// ---------------------------------------------------------------------------
__global__ __launch_bounds__(256) void chunk_intra_kernel(
        const float* __restrict__ xbc, const float* __restrict__ dts,
        const float* __restrict__ A_log, const float* __restrict__ Dv,
        float* __restrict__ yraw, float* __restrict__ Sc,
        float* __restrict__ dexp) {
    const int blk = blockIdx.x;      // ((b*32+h)*8 + c)
    const int c  = blk & 7;
    const int bh = blk >> 3;
    const int h  = bh & 31;
    const int b  = bh >> 5;
    const int rs0 = b * SEQ + c * CHUNK;

    __shared__ float sBn[64][68];    // B^T : [n][s]
    __shared__ float sX [64][68];    // C^T : [n][t], then U : [s][p]
    __shared__ float sMT[64][68];    // M^T : [s][t]
    __shared__ float sl[64], se[64], sdt[64];

    const int tid = threadIdx.x;
    const float A = -expf(A_log[h]);

    // ---- load B^T, C^T ----
    {
        const int row = tid >> 2;       // s / t
        const int cq  = tid & 3;
        const float* xrow = xbc + (size_t)(rs0 + row) * CONVDIM;
#pragma unroll
        for (int i = 0; i < 4; ++i) {
            const int n = cq * 16 + i * 4;
            float4 bv = *(const float4*)(xrow + DINNER + n);
            float4 cv = *(const float4*)(xrow + DINNER + DSTATE + n);
            sBn[n+0][row] = bv.x; sBn[n+1][row] = bv.y;
            sBn[n+2][row] = bv.z; sBn[n+3][row] = bv.w;
            sX [n+0][row] = cv.x; sX [n+1][row] = cv.y;
            sX [n+2][row] = cv.z; sX [n+3][row] = cv.w;
        }
    }

    // ---- dt + inclusive cumsum of dt*A (wave 0) ----
    if (tid < 64) {
        const float dtv = dts[(size_t)(rs0 + tid) * NHEADS + h];
        sdt[tid] = dtv;
        float v = dtv * A;
#pragma unroll
        for (int off = 1; off < 64; off <<= 1) {
            float o = __shfl_up(v, off, 64);
            if (tid >= off) v += o;
        }
        sl[tid] = v;
        const float ltot = __shfl(v, 63, 64);
        se[tid] = expf(ltot - v);
        dexp[(size_t)blk * 64 + tid] = expf(v);
    }
    __syncthreads();

    const int g0 = (tid >> 4) * 4;   // t0 / p0
    const int g1 = (tid & 15) * 4;   // s0 / p0 / n0

    // ---- M^T ----
    {
        const int t0 = g0, s0 = g1;
        float acc[4][4] = {};
        for (int n = 0; n < 64; ++n) {
            float4 ct = *(const float4*)&sX [n][t0];
            float4 bs = *(const float4*)&sBn[n][s0];
            float cta[4] = {ct.x, ct.y, ct.z, ct.w};
            float bsa[4] = {bs.x, bs.y, bs.z, bs.w};
#pragma unroll
            for (int i = 0; i < 4; ++i)
#pragma unroll
                for (int j = 0; j < 4; ++j) acc[i][j] += cta[i] * bsa[j];
        }
#pragma unroll
        for (int i = 0; i < 4; ++i) {
            const int t = t0 + i;
            const float lt = sl[t];
#pragma unroll
            for (int j = 0; j < 4; ++j) {
                const int s = s0 + j;
                sMT[s][t] = (s <= t) ? expf(lt - sl[s]) * acc[i][j] : 0.f;
            }
        }
    }
    __syncthreads();   // M ready; C^T space now free

    // ---- load U[s][p] = dt_s * x_s[p] into sX ----
    {
        const int row = tid >> 2;
        const int cq  = tid & 3;
        const float* xrow = xbc + (size_t)(rs0 + row) * CONVDIM + h * HEADDIM;
        const float dtv = sdt[row];
#pragma unroll
        for (int i = 0; i < 4; ++i) {
            const int p = cq * 16 + i * 4;
            float4 xv = *(const float4*)(xrow + p);
            sX[row][p+0] = dtv * xv.x; sX[row][p+1] = dtv * xv.y;
            sX[row][p+2] = dtv * xv.z; sX[row][p+3] = dtv * xv.w;
        }
    }
    __syncthreads();

    // ---- Y_intra = M @ U  (+ D*x) ----
    {
        const int t0 = g0, p0 = g1;
        float acc[4][4] = {};
        for (int s = 0; s < 64; ++s) {
            float4 mt = *(const float4*)&sMT[s][t0];
            float4 us = *(const float4*)&sX [s][p0];
            float mta[4] = {mt.x, mt.y, mt.z, mt.w};
            float usa[4] = {us.x, us.y, us.z, us.w};
#pragma unroll
            for (int i = 0; i < 4; ++i)
#pragma unroll
                for (int j = 0; j < 4; ++j) acc[i][j] += mta[i] * usa[j];
        }
        const float Dh = Dv[h];
#pragma unroll
        for (int i = 0; i < 4; ++i) {
            const int t = t0 + i;
            float4 xv = *(const float4*)(xbc + (size_t)(rs0 + t) * CONVDIM
                                         + h * HEADDIM + p0);
            float4 yv = make_float4(acc[i][0] + Dh * xv.x, acc[i][1] + Dh * xv.y,
                                    acc[i][2] + Dh * xv.z, acc[i][3] + Dh * xv.w);
            *(float4*)&yraw[(size_t)(rs0 + t) * DINNER + h * HEADDIM + p0] = yv;
        }
    }

    // ---- Sc[p][n] = sum_s se[s] * U[s][p] * B_s[n] ----
    {
        const int p0 = g0, n0 = g1;
        float acc[4][4] = {};
        for (int s = 0; s < 64; ++s) {
            const float es = se[s];
            float4 up = *(const float4*)&sX[s][p0];
            float upa[4] = {es * up.x, es * up.y, es * up.z, es * up.w};
            float bna[4] = {sBn[n0+0][s], sBn[n0+1][s], sBn[n0+2][s], sBn[n0+3][s]};
#pragma unroll
            for (int i = 0; i < 4; ++i)
#pragma unroll
                for (int j = 0; j < 4; ++j) acc[i][j] += upa[i] * bna[j];
        }
        float* scp = Sc + (size_t)blk * (HEADDIM * DSTATE);
#pragma unroll
        for (int i = 0; i < 4; ++i) {
            float4 v = make_float4(acc[i][0], acc[i][1], acc[i][2], acc[i][3]);
            *(float4*)&scp[(size_t)(p0 + i) * DSTATE + n0] = v;
        }
    }
}

// ---------------------------------------------------------------------------
// Pass B: inter-chunk state combine. h0ws[bhc] = state at START of chunk c.
// ---------------------------------------------------------------------------
__global__ __launch_bounds__(256) void state_combine_kernel(
        const float* __restrict__ Sc, const float* __restrict__ dexp,
        float* __restrict__ h0ws) {
    const int bh  = blockIdx.x;   // 0..63
    const int tid = threadIdx.x;
    float hreg[16];
#pragma unroll
    for (int k = 0; k < 16; ++k) hreg[k] = 0.f;
    for (int c = 0; c < NCHUNK; ++c) {
        const size_t base = (size_t)(bh * NCHUNK + c) * (HEADDIM * DSTATE);
        const float ac = dexp[(size_t)(bh * NCHUNK + c) * 64 + 63];
#pragma unroll
        for (int k = 0; k < 16; ++k) {
            const int e = tid + k * 256;
            h0ws[base + e] = hreg[k];
            hreg[k] = ac * hreg[k] + Sc[base + e];
        }
    }
}

// ---------------------------------------------------------------------------
// Pass C: Y_state[t][p] = exp(l_t) * sum_n C_t[n] * h0[p][n], added to yraw.
// ---------------------------------------------------------------------------
__global__ __launch_bounds__(256) void chunk_state_out_kernel(
        const float* __restrict__ xbc, const float* __restrict__ h0ws,
        const float* __restrict__ dexp, float* __restrict__ yraw) {
    const int blk = blockIdx.x;
    const int c  = blk & 7;
    if (c == 0) return;           // h0 == 0 for the first chunk
    const int bh = blk >> 3;
    const int h  = bh & 31;
    const int b  = bh >> 5;
    const int rs0 = b * SEQ + c * CHUNK;

    __shared__ float sCn[64][68];  // C^T [n][t]
    __shared__ float sH [64][68];  // h0^T [n][p]
    __shared__ float sdex[64];
    const int tid = threadIdx.x;
    {
        const int row = tid >> 2;   // t / p
        const int cq  = tid & 3;
        const float* xrow = xbc + (size_t)(rs0 + row) * CONVDIM + DINNER + DSTATE;
        const float* hrow = h0ws + (size_t)blk * (HEADDIM * DSTATE) + (size_t)row * DSTATE;
#pragma unroll
        for (int i = 0; i < 4; ++i) {
            const int n = cq * 16 + i * 4;
            float4 cv = *(const float4*)(xrow + n);
            float4 hv = *(const float4*)(hrow + n);
            sCn[n+0][row] = cv.x; sCn[n+1][row] = cv.y;
            sCn[n+2][row] = cv.z; sCn[n+3][row] = cv.w;
            sH [n+0][row] = hv.x; sH [n+1][row] = hv.y;
            sH [n+2][row] = hv.z; sH [n+3][row] = hv.w;
        }
    }
    if (tid < 64) sdex[tid] = dexp[(size_t)blk * 64 + tid];
    __syncthreads();

    const int t0 = (tid >> 4) * 4;
    const int p0 = (tid & 15) * 4;
    float acc[4][4] = {};
    for (int n = 0; n < 64; ++n) {
        float4 ct = *(const float4*)&sCn[n][t0];
        float4 hp = *(const float4*)&sH [n][p0];
        float cta[4] = {ct.x, ct.y, ct.z, ct.w};
        float hpa[4] = {hp.x, hp.y, hp.z, hp.w};
#pragma unroll
        for (int i = 0; i < 4; ++i)
#pragma unroll
            for (int j = 0; j < 4; ++j) acc[i][j] += cta[i] * hpa[j];
    }
#pragma unroll
    for (int i = 0; i < 4; ++i) {
        const float d = sdex[t0 + i];
        float* yp = &yraw[(size_t)(rs0 + t0 + i) * DINNER + h * HEADDIM + p0];
        float4 old = *(const float4*)yp;
        *(float4*)yp = make_float4(old.x + d * acc[i][0], old.y + d * acc[i][1],
                                   old.z + d * acc[i][2], old.w + d * acc[i][3]);
    }
}

// ---------------------------------------------------------------------------
// y = y * silu(z); y = y * rsqrt(mean(y^2) + eps) * norm_w.  In-place on yraw.
// ---------------------------------------------------------------------------
__global__ __launch_bounds__(256) void gate_norm_kernel(
        const float* __restrict__ zxbcdt, float* __restrict__ y,
        const float* __restrict__ nw) {
    const int rs = blockIdx.x;
    const int t  = threadIdx.x;
    const float* z = zxbcdt + (size_t)rs * DINPROJ;
    float* yr = y + (size_t)rs * DINNER;

    float vals[8];
    float ss = 0.f;
#pragma unroll
    for (int i = 0; i < 8; ++i) {
        const int c = t + i * 256;
        const float zv = z[c];
        const float v  = yr[c] * (zv / (1.f + expf(-zv)));
        vals[i] = v;
        ss += v * v;
    }
#pragma unroll
    for (int off = 32; off > 0; off >>= 1) ss += __shfl_down(ss, off, 64);
    __shared__ float red[4];
    if ((t & 63) == 0) red[t >> 6] = ss;
    __syncthreads();
    const float tot   = red[0] + red[1] + red[2] + red[3];
    const float scale = rsqrtf(tot / (float)DINNER + RMS_EPS);
#pragma unroll
    for (int i = 0; i < 8; ++i) {
        const int c = t + i * 256;
        yr[c] = vals[i] * scale * nw[c];
    }
}

// ---------------------------------------------------------------------------
__global__ __launch_bounds__(256) void pred_cur_kernel(
        const float* __restrict__ hout, const float* __restrict__ w,
        const float* __restrict__ bvec, float* __restrict__ out) {
    const int rs = blockIdx.x;
    const int t  = threadIdx.x;
    const float* hr = hout + (size_t)rs * DMODEL;
    float p0 = 0.f, p1 = 0.f, p2 = 0.f;
    for (int i = t; i < DMODEL; i += 256) {
        const float hv = hr[i];
        p0 += hv * w[i];
        p1 += hv * w[DMODEL + i];
        p2 += hv * w[2 * DMODEL + i];
    }
#pragma unroll
    for (int off = 32; off > 0; off >>= 1) {
        p0 += __shfl_down(p0, off, 64);
        p1 += __shfl_down(p1, off, 64);
        p2 += __shfl_down(p2, off, 64);
    }
    __shared__ float red[4][3];
    if ((t & 63) == 0) {
        red[t >> 6][0] = p0; red[t >> 6][1] = p1; red[t >> 6][2] = p2;
    }
    __syncthreads();
    if (t < 3) {
        const float s = red[0][t] + red[1][t] + red[2][t] + red[3][t];
        out[(size_t)rs * VNUM + t] = s + bvec[t];
    }
}

__global__ __launch_bounds__(256) void pred_fut_kernel(
        const float* __restrict__ hout, const float* __restrict__ w,
        const float* __restrict__ bvec, float* __restrict__ out) {
    const int blk = blockIdx.x;
    const int b = blk / (HORIZON * VNUM);
    const int j = blk % (HORIZON * VNUM);
    const float* hr = hout + ((size_t)b * SEQ + (SEQ - 1)) * DMODEL;
    const float* wr = w + (size_t)j * DMODEL;
    float pv = 0.f;
    for (int i = threadIdx.x; i < DMODEL; i += 256) pv += hr[i] * wr[i];
#pragma unroll
    for (int off = 32; off > 0; off >>= 1) pv += __shfl_down(pv, off, 64);
    __shared__ float red[4];
    if ((threadIdx.x & 63) == 0) red[threadIdx.x >> 6] = pv;
    __syncthreads();
    if (threadIdx.x == 0)
        out[b * (HORIZON * VNUM) + j] = red[0] + red[1] + red[2] + red[3] + bvec[j];
}

// ---------------------------------------------------------------------------
extern "C" void kernel_launch(void* const* d_in, const int* in_sizes, int n_in,
                              void* d_out, int out_size, void* d_ws, size_t ws_size,
                              hipStream_t stream) {
    const float* embed      = (const float*)d_in[0];
    const float* in_proj_w  = (const float*)d_in[1];
    const float* conv_w     = (const float*)d_in[2];
    const float* conv_b     = (const float*)d_in[3];
    const float* dt_bias    = (const float*)d_in[4];
    const float* A_log      = (const float*)d_in[5];
    const float* Dv         = (const float*)d_in[6];
    const float* norm_w     = (const float*)d_in[7];
    const float* out_proj_w = (const float*)d_in[8];
    const float* dec_cur_w  = (const float*)d_in[9];
    const float* dec_cur_b  = (const float*)d_in[10];
    const float* dec_fut_w  = (const float*)d_in[11];
    const float* dec_fut_b  = (const float*)d_in[12];

    float* ws     = (float*)d_ws;
    float* zxbcdt = ws;                                   // BS*DINPROJ
    float* xbc    = zxbcdt + (size_t)BS * DINPROJ;        // BS*CONVDIM
    float* dts    = xbc    + (size_t)BS * CONVDIM;        // BS*NHEADS
    float* yraw   = dts    + (size_t)BS * NHEADS;         // BS*DINNER
    float* hout   = yraw   + (size_t)BS * DINNER;         // BS*DMODEL
    float* Sc     = hout   + (size_t)BS * DMODEL;         // 512*4096
    float* h0ws   = Sc     + (size_t)BATCH*NHEADS*NCHUNK*HEADDIM*DSTATE; // 512*4096
    float* dexp   = h0ws   + (size_t)BATCH*NHEADS*NCHUNK*HEADDIM*DSTATE; // 512*64

    float* out = (float*)d_out;

    // 1. in-projection GEMM
    gemm_nt<BS, DINPROJ, DMODEL>
        <<<dim3((DINPROJ + 63) / 64, BS / 64), 256, 0, stream>>>(embed, in_proj_w, zxbcdt);

    // 2. causal conv + SiLU ; softplus(dt)
    conv_silu_kernel<<<(BS * CONVDIM + 255) / 256, 256, 0, stream>>>(zxbcdt, conv_w, conv_b, xbc);
    dt_softplus_kernel<<<(BS * NHEADS + 255) / 256, 256, 0, stream>>>(zxbcdt, dt_bias, dts);

    // 3. chunked SSD scan (3 passes)
    chunk_intra_kernel<<<BATCH * NHEADS * NCHUNK, 256, 0, stream>>>(
        xbc, dts, A_log, Dv, yraw, Sc, dexp);
    state_combine_kernel<<<BATCH * NHEADS, 256, 0, stream>>>(Sc, dexp, h0ws);
    chunk_state_out_kernel<<<BATCH * NHEADS * NCHUNK, 256, 0, stream>>>(
        xbc, h0ws, dexp, yraw);

    // 4. gate + RMSNorm (in place)
    gate_norm_kernel<<<BS, 256, 0, stream>>>(zxbcdt, yraw, norm_w);

    // 5. out-projection GEMM
    gemm_nt<BS, DMODEL, DINNER>
        <<<dim3(DMODEL / 64, BS / 64), 256, 0, stream>>>(yraw, out_proj_w, hout);

    // 6. decoders
    pred_cur_kernel<<<BS, 256, 0, stream>>>(hout, dec_cur_w, dec_cur_b, out);
    pred_fut_kernel<<<BATCH * HORIZON * VNUM, 256, 0, stream>>>(hout, dec_fut_w, dec_fut_b,
                                                                out + BS * VNUM);
}

// Round 3
// 208.265 us; speedup vs baseline: 3.2829x; 1.9334x over previous
//
#include <hip/hip_runtime.h>
#include <hip/hip_bf16.h>

#define BATCH   2
#define SEQ     512
#define DMODEL  1024
#define DSTATE  64
#define HEADDIM 64
#define DCONV   4
#define VNUM    3
#define HORIZON 20
#define DINNER  2048
#define NHEADS  32
#define CONVDIM 2176   // DINNER + 2*DSTATE
#define DINPROJ 4256   // 2*DINNER + 2*DSTATE + NHEADS
#define NPAD1   4352   // DINPROJ padded to 128
#define BS      (BATCH*SEQ)   // 1024
#define RMS_EPS 1e-5f
#define CHUNK   64
#define NCHUNK  (SEQ/CHUNK)   // 8

typedef __attribute__((ext_vector_type(8))) short bf16x8;
typedef __attribute__((ext_vector_type(4))) float f32x4;

__device__ __forceinline__ unsigned short f2b(float x) {
    union { float f; unsigned u; } v; v.f = x;
    return (unsigned short)((v.u + 0x7fffu + ((v.u >> 16) & 1u)) >> 16);  // RNE
}

__device__ __forceinline__ void async16(const void* g, const void* l) {
    __builtin_amdgcn_global_load_lds(
        (const __attribute__((address_space(1))) unsigned int*)g,
        (__attribute__((address_space(3))) unsigned int*)l, 16, 0, 0);
}

// ---------------------------------------------------------------------------
// bf16 MFMA GEMM (NT): C[M,N]fp32 = A[M,KD]bf16 * B[Npad,KD]bf16^T.
// 256 threads = 4 waves (2x2), wave tile WMxWN = (FM*16)x(FN*16), BK=32.
// m97 structure: global_load_lds width-16 staging + 2-barrier K-loop.
// B must have >= gridDim.x*BN rows (pad rows zero-filled); store guarded by N.
// ---------------------------------------------------------------------------
template<int BM, int BN, int FM, int FN, int KD>
__global__ __launch_bounds__(256) void gemm_bf16(const short* __restrict__ A,
                                                 const short* __restrict__ B,
                                                 float* __restrict__ C, int N) {
    constexpr int WM = FM * 16, WN = FN * 16;
    static_assert(BM == 2 * WM && BN == 2 * WN, "2x2 waves");
    __shared__ __align__(16) short At[BM * 32];
    __shared__ __align__(16) short Bt[BN * 32];
    const int t    = threadIdx.x;
    const int lane = t & 63;
    const int w    = t >> 6;
    const int wm   = (w >> 1) * WM, wn = (w & 1) * WN;
    const int row0 = blockIdx.y * BM, col0 = blockIdx.x * BN;
    const int fr   = lane & 15;     // frag row/col
    const int kq   = lane >> 4;     // k-quad (x8)
    const int lr   = t >> 2;        // staging row 0..63
    const int lc   = (t & 3) * 8;   // staging k-col (8 bf16 = 16B)

    const short* Ag = A + (size_t)(row0 + lr) * KD + lc;
    const short* Bg = B + (size_t)(col0 + lr) * KD + lc;

    f32x4 acc[FM][FN];
#pragma unroll
    for (int i = 0; i < FM; ++i)
#pragma unroll
        for (int j = 0; j < FN; ++j)
#pragma unroll
            for (int r = 0; r < 4; ++r) acc[i][j][r] = 0.f;

    for (int k0 = 0; k0 < KD; k0 += 32) {
        __syncthreads();   // prev iteration's LDS reads complete
#pragma unroll
        for (int i = 0; i < BM / 64; ++i)
            async16(Ag + (size_t)i * 64 * KD + k0, (const char*)At + i * 4096 + t * 16);
#pragma unroll
        for (int i = 0; i < BN / 64; ++i)
            async16(Bg + (size_t)i * 64 * KD + k0, (const char*)Bt + i * 4096 + t * 16);
        __syncthreads();   // vmcnt(0) drain + barrier: tiles visible

        bf16x8 af[FM], bv[FN];
#pragma unroll
        for (int i = 0; i < FM; ++i)
            af[i] = *(const bf16x8*)&At[(wm + i * 16 + fr) * 32 + kq * 8];
#pragma unroll
        for (int j = 0; j < FN; ++j)
            bv[j] = *(const bf16x8*)&Bt[(wn + j * 16 + fr) * 32 + kq * 8];
#pragma unroll
        for (int i = 0; i < FM; ++i)
#pragma unroll
            for (int j = 0; j < FN; ++j)
                acc[i][j] = __builtin_amdgcn_mfma_f32_16x16x32_bf16(
                    af[i], bv[j], acc[i][j], 0, 0, 0);
    }

    // C/D layout (m89-verified): col = lane&15, row = (lane>>4)*4 + reg
    const int orow = lane >> 4;
#pragma unroll
    for (int i = 0; i < FM; ++i)
#pragma unroll
        for (int j = 0; j < FN; ++j) {
            const int col = col0 + wn + j * 16 + fr;
            if (col < N) {
#pragma unroll
                for (int r = 0; r < 4; ++r) {
                    const int row = row0 + wm + i * 16 + orow * 4 + r;
                    C[(size_t)row * N + col] = acc[i][j][r];
                }
            }
        }
}

// ---------------------------------------------------------------------------
// fp32 -> bf16 casts
// ---------------------------------------------------------------------------
__global__ __launch_bounds__(256) void cast_bf16_kernel(const float* __restrict__ in,
                                                        short* __restrict__ out, int n4) {
    const int i = blockIdx.x * 256 + threadIdx.x;
    if (i >= n4) return;
    float4 v = *(const float4*)(in + (size_t)i * 4);
    short4 o = make_short4((short)f2b(v.x), (short)f2b(v.y),
                           (short)f2b(v.z), (short)f2b(v.w));
    *(short4*)(out + (size_t)i * 4) = o;
}

// in_proj_w [4256][1024] -> bf16 [4352][1024], tail rows zeroed
__global__ __launch_bounds__(256) void cast_pad_kernel(const float* __restrict__ in,
                                                       short* __restrict__ out) {
    const int i = blockIdx.x * 256 + threadIdx.x;   // < NPAD1*DMODEL/4
    const size_t e0 = (size_t)i * 4;
    const int row = (int)(e0 / DMODEL);
    short4 o;
    if (row < DINPROJ) {
        float4 v = *(const float4*)(in + e0);
        o = make_short4((short)f2b(v.x), (short)f2b(v.y),
                        (short)f2b(v.z), (short)f2b(v.w));
    } else {
        o = make_short4(0, 0, 0, 0);
    }
    *(short4*)(out + e0) = o;
}

// ---------------------------------------------------------------------------
// Causal conv1d (width 4) + bias + SiLU over the xBC slice of zxbcdt.
// ---------------------------------------------------------------------------
__global__ __launch_bounds__(256) void conv_silu_kernel(
        const float* __restrict__ zxbcdt, const float* __restrict__ cw,
        const float* __restrict__ cb, float* __restrict__ xbc) {
    const int idx = blockIdx.x * 256 + threadIdx.x;
    if (idx >= BS * CONVDIM) return;
    const int c  = idx % CONVDIM;
    const int rs = idx / CONVDIM;
    const int s  = rs % SEQ;
    const float* src = zxbcdt + (size_t)rs * DINPROJ + DINNER + c;
    float acc = cb[c];
    const float w0 = cw[c * 4 + 0], w1 = cw[c * 4 + 1];
    const float w2 = cw[c * 4 + 2], w3 = cw[c * 4 + 3];
    if (s >= 3) acc += w0 * src[-3 * DINPROJ];
    if (s >= 2) acc += w1 * src[-2 * DINPROJ];
    if (s >= 1) acc += w2 * src[-1 * DINPROJ];
    acc += w3 * src[0];
    acc = acc / (1.f + expf(-acc));   // SiLU
    xbc[(size_t)rs * CONVDIM + c] = acc;
}

// ---------------------------------------------------------------------------
// dt = softplus(dt_raw + dt_bias)
// ---------------------------------------------------------------------------
__global__ __launch_bounds__(256) void dt_softplus_kernel(
        const float* __restrict__ zxbcdt, const float* __restrict__ dt_bias,
        float* __restrict__ dts) {
    const int idx = blockIdx.x * 256 + threadIdx.x;
    if (idx >= BS * NHEADS) return;
    const int h  = idx % NHEADS;
    const int rs = idx / NHEADS;
    const float v = zxbcdt[(size_t)rs * DINPROJ + DINNER + CONVDIM + h] + dt_bias[h];
    const float sp = fmaxf(v, 0.f) + log1pf(expf(-fabsf(v)));
    dts[idx] = sp;
}

// ---------------------------------------------------------------------------
// Chunked SSD scan, pass A (per (b,h,chunk)): M^T, Y_intra, chunk state Sc,
// per-step decay dexp. See round-2 version for derivation.
// ---------------------------------------------------------------------------
__global__ __launch_bounds__(256) void chunk_intra_kernel(
        const float* __restrict__ xbc, const float* __restrict__ dts,
        const float* __restrict__ A_log, const float* __restrict__ Dv,
        float* __restrict__ yraw, float* __restrict__ Sc,
        float* __restrict__ dexp) {
    const int blk = blockIdx.x;      // ((b*32+h)*8 + c)
    const int c  = blk & 7;
    const int bh = blk >> 3;
    const int h  = bh & 31;
    const int b  = bh >> 5;
    const int rs0 = b * SEQ + c * CHUNK;

    __shared__ float sBn[64][68];    // B^T : [n][s]
    __shared__ float sX [64][68];    // C^T : [n][t], then U : [s][p]
    __shared__ float sMT[64][68];    // M^T : [s][t]
    __shared__ float sl[64], se[64], sdt[64];

    const int tid = threadIdx.x;
    const float A = -expf(A_log[h]);

    {
        const int row = tid >> 2;
        const int cq  = tid & 3;
        const float* xrow = xbc + (size_t)(rs0 + row) * CONVDIM;
#pragma unroll
        for (int i = 0; i < 4; ++i) {
            const int n = cq * 16 + i * 4;
            float4 bv = *(const float4*)(xrow + DINNER + n);
            float4 cv = *(const float4*)(xrow + DINNER + DSTATE + n);
            sBn[n+0][row] = bv.x; sBn[n+1][row] = bv.y;
            sBn[n+2][row] = bv.z; sBn[n+3][row] = bv.w;
            sX [n+0][row] = cv.x; sX [n+1][row] = cv.y;
            sX [n+2][row] = cv.z; sX [n+3][row] = cv.w;
        }
    }

    if (tid < 64) {
        const float dtv = dts[(size_t)(rs0 + tid) * NHEADS + h];
        sdt[tid] = dtv;
        float v = dtv * A;
#pragma unroll
        for (int off = 1; off < 64; off <<= 1) {
            float o = __shfl_up(v, off, 64);
            if (tid >= off) v += o;
        }
        sl[tid] = v;
        const float ltot = __shfl(v, 63, 64);
        se[tid] = expf(ltot - v);
        dexp[(size_t)blk * 64 + tid] = expf(v);
    }
    __syncthreads();

    const int g0 = (tid >> 4) * 4;
    const int g1 = (tid & 15) * 4;

    {   // M^T
        const int t0 = g0, s0 = g1;
        float acc[4][4] = {};
        for (int n = 0; n < 64; ++n) {
            float4 ct = *(const float4*)&sX [n][t0];
            float4 bs = *(const float4*)&sBn[n][s0];
            float cta[4] = {ct.x, ct.y, ct.z, ct.w};
            float bsa[4] = {bs.x, bs.y, bs.z, bs.w};
#pragma unroll
            for (int i = 0; i < 4; ++i)
#pragma unroll
                for (int j = 0; j < 4; ++j) acc[i][j] += cta[i] * bsa[j];
        }
#pragma unroll
        for (int i = 0; i < 4; ++i) {
            const int t = t0 + i;
            const float lt = sl[t];
#pragma unroll
            for (int j = 0; j < 4; ++j) {
                const int s = s0 + j;
                sMT[s][t] = (s <= t) ? expf(lt - sl[s]) * acc[i][j] : 0.f;
            }
        }
    }
    __syncthreads();

    {   // U = dt*x into sX
        const int row = tid >> 2;
        const int cq  = tid & 3;
        const float* xrow = xbc + (size_t)(rs0 + row) * CONVDIM + h * HEADDIM;
        const float dtv = sdt[row];
#pragma unroll
        for (int i = 0; i < 4; ++i) {
            const int p = cq * 16 + i * 4;
            float4 xv = *(const float4*)(xrow + p);
            sX[row][p+0] = dtv * xv.x; sX[row][p+1] = dtv * xv.y;
            sX[row][p+2] = dtv * xv.z; sX[row][p+3] = dtv * xv.w;
        }
    }
    __syncthreads();

    {   // Y_intra = M @ U (+ D*x)
        const int t0 = g0, p0 = g1;
        float acc[4][4] = {};
        for (int s = 0; s < 64; ++s) {
            float4 mt = *(const float4*)&sMT[s][t0];
            float4 us = *(const float4*)&sX [s][p0];
            float mta[4] = {mt.x, mt.y, mt.z, mt.w};
            float usa[4] = {us.x, us.y, us.z, us.w};
#pragma unroll
            for (int i = 0; i < 4; ++i)
#pragma unroll
                for (int j = 0; j < 4; ++j) acc[i][j] += mta[i] * usa[j];
        }
        const float Dh = Dv[h];
#pragma unroll
        for (int i = 0; i < 4; ++i) {
            const int t = t0 + i;
            float4 xv = *(const float4*)(xbc + (size_t)(rs0 + t) * CONVDIM
                                         + h * HEADDIM + p0);
            float4 yv = make_float4(acc[i][0] + Dh * xv.x, acc[i][1] + Dh * xv.y,
                                    acc[i][2] + Dh * xv.z, acc[i][3] + Dh * xv.w);
            *(float4*)&yraw[(size_t)(rs0 + t) * DINNER + h * HEADDIM + p0] = yv;
        }
    }

    {   // Sc[p][n] = sum_s se[s]*U[s][p]*B_s[n]
        const int p0 = g0, n0 = g1;
        float acc[4][4] = {};
        for (int s = 0; s < 64; ++s) {
            const float es = se[s];
            float4 up = *(const float4*)&sX[s][p0];
            float upa[4] = {es * up.x, es * up.y, es * up.z, es * up.w};
            float bna[4] = {sBn[n0+0][s], sBn[n0+1][s], sBn[n0+2][s], sBn[n0+3][s]};
#pragma unroll
            for (int i = 0; i < 4; ++i)
#pragma unroll
                for (int j = 0; j < 4; ++j) acc[i][j] += upa[i] * bna[j];
        }
        float* scp = Sc + (size_t)blk * (HEADDIM * DSTATE);
#pragma unroll
        for (int i = 0; i < 4; ++i) {
            float4 v = make_float4(acc[i][0], acc[i][1], acc[i][2], acc[i][3]);
            *(float4*)&scp[(size_t)(p0 + i) * DSTATE + n0] = v;
        }
    }
}

// ---------------------------------------------------------------------------
// Pass B: inter-chunk state combine.
// ---------------------------------------------------------------------------
__global__ __launch_bounds__(256) void state_combine_kernel(
        const float* __restrict__ Sc, const float* __restrict__ dexp,
        float* __restrict__ h0ws) {
    const int bh  = blockIdx.x;
    const int tid = threadIdx.x;
    float hreg[16];
#pragma unroll
    for (int k = 0; k < 16; ++k) hreg[k] = 0.f;
    for (int c = 0; c < NCHUNK; ++c) {
        const size_t base = (size_t)(bh * NCHUNK + c) * (HEADDIM * DSTATE);
        const float ac = dexp[(size_t)(bh * NCHUNK + c) * 64 + 63];
#pragma unroll
        for (int k = 0; k < 16; ++k) {
            const int e = tid + k * 256;
            h0ws[base + e] = hreg[k];
            hreg[k] = ac * hreg[k] + Sc[base + e];
        }
    }
}

// ---------------------------------------------------------------------------
// Pass C: Y_state added to yraw.
// ---------------------------------------------------------------------------
__global__ __launch_bounds__(256) void chunk_state_out_kernel(
        const float* __restrict__ xbc, const float* __restrict__ h0ws,
        const float* __restrict__ dexp, float* __restrict__ yraw) {
    const int blk = blockIdx.x;
    const int c  = blk & 7;
    if (c == 0) return;
    const int bh = blk >> 3;
    const int h  = bh & 31;
    const int b  = bh >> 5;
    const int rs0 = b * SEQ + c * CHUNK;

    __shared__ float sCn[64][68];
    __shared__ float sH [64][68];
    __shared__ float sdex[64];
    const int tid = threadIdx.x;
    {
        const int row = tid >> 2;
        const int cq  = tid & 3;
        const float* xrow = xbc + (size_t)(rs0 + row) * CONVDIM + DINNER + DSTATE;
        const float* hrow = h0ws + (size_t)blk * (HEADDIM * DSTATE) + (size_t)row * DSTATE;
#pragma unroll
        for (int i = 0; i < 4; ++i) {
            const int n = cq * 16 + i * 4;
            float4 cv = *(const float4*)(xrow + n);
            float4 hv = *(const float4*)(hrow + n);
            sCn[n+0][row] = cv.x; sCn[n+1][row] = cv.y;
            sCn[n+2][row] = cv.z; sCn[n+3][row] = cv.w;
            sH [n+0][row] = hv.x; sH [n+1][row] = hv.y;
            sH [n+2][row] = hv.z; sH [n+3][row] = hv.w;
        }
    }
    if (tid < 64) sdex[tid] = dexp[(size_t)blk * 64 + tid];
    __syncthreads();

    const int t0 = (tid >> 4) * 4;
    const int p0 = (tid & 15) * 4;
    float acc[4][4] = {};
    for (int n = 0; n < 64; ++n) {
        float4 ct = *(const float4*)&sCn[n][t0];
        float4 hp = *(const float4*)&sH [n][p0];
        float cta[4] = {ct.x, ct.y, ct.z, ct.w};
        float hpa[4] = {hp.x, hp.y, hp.z, hp.w};
#pragma unroll
        for (int i = 0; i < 4; ++i)
#pragma unroll
            for (int j = 0; j < 4; ++j) acc[i][j] += cta[i] * hpa[j];
    }
#pragma unroll
    for (int i = 0; i < 4; ++i) {
        const float d = sdex[t0 + i];
        float* yp = &yraw[(size_t)(rs0 + t0 + i) * DINNER + h * HEADDIM + p0];
        float4 old = *(const float4*)yp;
        *(float4*)yp = make_float4(old.x + d * acc[i][0], old.y + d * acc[i][1],
                                   old.z + d * acc[i][2], old.w + d * acc[i][3]);
    }
}

// ---------------------------------------------------------------------------
// gate + RMSNorm; writes bf16 for the MFMA out-projection.
// ---------------------------------------------------------------------------
__global__ __launch_bounds__(256) void gate_norm_kernel(
        const float* __restrict__ zxbcdt, const float* __restrict__ y,
        short* __restrict__ yb, const float* __restrict__ nw) {
    const int rs = blockIdx.x;
    const int t  = threadIdx.x;
    const float* z = zxbcdt + (size_t)rs * DINPROJ;
    const float* yr = y + (size_t)rs * DINNER;
    short* yo = yb + (size_t)rs * DINNER;

    float vals[8];
    float ss = 0.f;
#pragma unroll
    for (int i = 0; i < 8; ++i) {
        const int c = t + i * 256;
        const float zv = z[c];
        const float v  = yr[c] * (zv / (1.f + expf(-zv)));
        vals[i] = v;
        ss += v * v;
    }
#pragma unroll
    for (int off = 32; off > 0; off >>= 1) ss += __shfl_down(ss, off, 64);
    __shared__ float red[4];
    if ((t & 63) == 0) red[t >> 6] = ss;
    __syncthreads();
    const float tot   = red[0] + red[1] + red[2] + red[3];
    const float scale = rsqrtf(tot / (float)DINNER + RMS_EPS);
#pragma unroll
    for (int i = 0; i < 8; ++i) {
        const int c = t + i * 256;
        yo[c] = (short)f2b(vals[i] * scale * nw[c]);
    }
}

// ---------------------------------------------------------------------------
__global__ __launch_bounds__(256) void pred_cur_kernel(
        const float* __restrict__ hout, const float* __restrict__ w,
        const float* __restrict__ bvec, float* __restrict__ out) {
    const int rs = blockIdx.x;
    const int t  = threadIdx.x;
    const float* hr = hout + (size_t)rs * DMODEL;
    float p0 = 0.f, p1 = 0.f, p2 = 0.f;
    for (int i = t; i < DMODEL; i += 256) {
        const float hv = hr[i];
        p0 += hv * w[i];
        p1 += hv * w[DMODEL + i];
        p2 += hv * w[2 * DMODEL + i];
    }
#pragma unroll
    for (int off = 32; off > 0; off >>= 1) {
        p0 += __shfl_down(p0, off, 64);
        p1 += __shfl_down(p1, off, 64);
        p2 += __shfl_down(p2, off, 64);
    }
    __shared__ float red[4][3];
    if ((t & 63) == 0) {
        red[t >> 6][0] = p0; red[t >> 6][1] = p1; red[t >> 6][2] = p2;
    }
    __syncthreads();
    if (t < 3) {
        const float s = red[0][t] + red[1][t] + red[2][t] + red[3][t];
        out[(size_t)rs * VNUM + t] = s + bvec[t];
    }
}

__global__ __launch_bounds__(256) void pred_fut_kernel(
        const float* __restrict__ hout, const float* __restrict__ w,
        const float* __restrict__ bvec, float* __restrict__ out) {
    const int blk = blockIdx.x;
    const int b = blk / (HORIZON * VNUM);
    const int j = blk % (HORIZON * VNUM);
    const float* hr = hout + ((size_t)b * SEQ + (SEQ - 1)) * DMODEL;
    const float* wr = w + (size_t)j * DMODEL;
    float pv = 0.f;
    for (int i = threadIdx.x; i < DMODEL; i += 256) pv += hr[i] * wr[i];
#pragma unroll
    for (int off = 32; off > 0; off >>= 1) pv += __shfl_down(pv, off, 64);
    __shared__ float red[4];
    if ((threadIdx.x & 63) == 0) red[threadIdx.x >> 6] = pv;
    __syncthreads();
    if (threadIdx.x == 0)
        out[b * (HORIZON * VNUM) + j] = red[0] + red[1] + red[2] + red[3] + bvec[j];
}

// ---------------------------------------------------------------------------
extern "C" void kernel_launch(void* const* d_in, const int* in_sizes, int n_in,
                              void* d_out, int out_size, void* d_ws, size_t ws_size,
                              hipStream_t stream) {
    const float* embed      = (const float*)d_in[0];
    const float* in_proj_w  = (const float*)d_in[1];
    const float* conv_w     = (const float*)d_in[2];
    const float* conv_b     = (const float*)d_in[3];
    const float* dt_bias    = (const float*)d_in[4];
    const float* A_log      = (const float*)d_in[5];
    const float* Dv         = (const float*)d_in[6];
    const float* norm_w     = (const float*)d_in[7];
    const float* out_proj_w = (const float*)d_in[8];
    const float* dec_cur_w  = (const float*)d_in[9];
    const float* dec_cur_b  = (const float*)d_in[10];
    const float* dec_fut_w  = (const float*)d_in[11];
    const float* dec_fut_b  = (const float*)d_in[12];

    float* ws     = (float*)d_ws;
    float* zxbcdt = ws;                                   // BS*DINPROJ
    float* xbc    = zxbcdt + (size_t)BS * DINPROJ;        // BS*CONVDIM
    float* dts    = xbc    + (size_t)BS * CONVDIM;        // BS*NHEADS
    float* yraw   = dts    + (size_t)BS * NHEADS;         // BS*DINNER
    float* hout   = yraw   + (size_t)BS * DINNER;         // BS*DMODEL
    float* Sc     = hout   + (size_t)BS * DMODEL;
    float* h0ws   = Sc     + (size_t)BATCH*NHEADS*NCHUNK*HEADDIM*DSTATE;
    float* dexp   = h0ws   + (size_t)BATCH*NHEADS*NCHUNK*HEADDIM*DSTATE;
    short* embB   = (short*)(dexp + (size_t)BATCH*NHEADS*NCHUNK*64);
    short* ipwB   = embB + (size_t)BS * DMODEL;           // NPAD1*DMODEL bf16
    short* opwB   = ipwB + (size_t)NPAD1 * DMODEL;        // DMODEL*DINNER bf16
    short* ybB    = opwB + (size_t)DMODEL * DINNER;       // BS*DINNER bf16

    float* out = (float*)d_out;

    // 0. casts to bf16
    cast_bf16_kernel<<<(BS * DMODEL / 4 + 255) / 256, 256, 0, stream>>>(
        embed, embB, BS * DMODEL / 4);
    cast_pad_kernel<<<NPAD1 * DMODEL / 4 / 256, 256, 0, stream>>>(in_proj_w, ipwB);
    cast_bf16_kernel<<<(DMODEL * DINNER / 4 + 255) / 256, 256, 0, stream>>>(
        out_proj_w, opwB, DMODEL * DINNER / 4);

    // 1. in-projection GEMM (bf16 MFMA): [1024,1024] x [4352,1024]^T
    gemm_bf16<128, 128, 4, 4, DMODEL>
        <<<dim3(NPAD1 / 128, BS / 128), 256, 0, stream>>>(embB, ipwB, zxbcdt, DINPROJ);

    // 2. causal conv + SiLU ; softplus(dt)
    conv_silu_kernel<<<(BS * CONVDIM + 255) / 256, 256, 0, stream>>>(zxbcdt, conv_w, conv_b, xbc);
    dt_softplus_kernel<<<(BS * NHEADS + 255) / 256, 256, 0, stream>>>(zxbcdt, dt_bias, dts);

    // 3. chunked SSD scan
    chunk_intra_kernel<<<BATCH * NHEADS * NCHUNK, 256, 0, stream>>>(
        xbc, dts, A_log, Dv, yraw, Sc, dexp);
    state_combine_kernel<<<BATCH * NHEADS, 256, 0, stream>>>(Sc, dexp, h0ws);
    chunk_state_out_kernel<<<BATCH * NHEADS * NCHUNK, 256, 0, stream>>>(
        xbc, h0ws, dexp, yraw);

    // 4. gate + RMSNorm -> bf16
    gate_norm_kernel<<<BS, 256, 0, stream>>>(zxbcdt, yraw, ybB, norm_w);

    // 5. out-projection GEMM (bf16 MFMA): [1024,2048] x [1024,2048]^T
    gemm_bf16<64, 64, 2, 2, DINNER>
        <<<dim3(DMODEL / 64, BS / 64), 256, 0, stream>>>(ybB, opwB, hout, DMODEL);

    // 6. decoders
    pred_cur_kernel<<<BS, 256, 0, stream>>>(hout, dec_cur_w, dec_cur_b, out);
    pred_fut_kernel<<<BATCH * HORIZON * VNUM, 256, 0, stream>>>(hout, dec_fut_w, dec_fut_b,
                                                                out + BS * VNUM);
}